// Round 11
// baseline (337.096 us; speedup 1.0000x reference)
//
#include <hip/hip_runtime.h>
#include <hip/hip_bf16.h>
#include <hip/hip_fp16.h>
#include <stdint.h>

// LightGCN on MI355X, round 14.
// R13 post-mortem: bcnt replication = null (bank math: 2 lanes/bank is
// free; k_bucket is LDS-atomic THROUGHPUT bound ~45-50us). spmv x3 at its
// proven floor (58.8us; insensitive to writes/MLP; FETCH pinned 182MB).
// Remaining non-floor: k_build (~40us: 4 sub-blocks each count ALL 512
// nodes = 16K atomics/block) and k_z0 (~10us + gap).
// R14: (1) k_build sub-block counts only its OWN 128 nodes per-node (4K
// atomics); totals of other quarters via __ballot+__popcll per iteration
// (~300 scalar atomics) -> quarter prefix gives csrc base. (2) z0 fused
// into k_build (degrees already in LDS); zA un-aliased from staging (zB
// takes the overlay; zB is first written after staging dies). dinv array
// deleted (rec carries it). Zero rows via two 128B memsets.
// k_bucket = R9 exact. spmv = R9 exact. Numerics unchanged.

#define N_NODES 100000
#define N_EDGES 3200000
#define DIM 64

#define BSH 9                // 512 nodes per bucket
#define BNODES 512
#define NB 196               // ceil(100000/512)
#define CAP 20480            // staging slots per bucket (mean 16327)

#define CHUNK 8192           // edges per k_bucket block
#define NBLK1 ((N_EDGES + CHUNK - 1) / CHUNK)  // 391

// ---- level 1: bucket edges by dst range (dst>>9) ----
__global__ __launch_bounds__(256) void k_bucket(const int* __restrict__ ei,
                                                int* __restrict__ gcursor,
                                                int* __restrict__ staging) {
    __shared__ int stage[CHUNK];            // packed (row<<9)|dstLocal
    __shared__ unsigned char sbkt[CHUNK];   // bucket id per staged entry
    __shared__ int bcnt[NB];
    __shared__ int boff[NB];
    __shared__ int bstart[NB];
    __shared__ int gbase[NB];
    __shared__ int wt[4];

    int t = threadIdx.x;
    int e0 = blockIdx.x * CHUNK;
    int nblk = min(CHUNK, N_EDGES - e0);
    int nvec = nblk >> 2;

    const int4* col4 = (const int4*)(ei + N_EDGES + e0);
    const int4* row4 = (const int4*)(ei + e0);

    for (int i = t; i < NB; i += 256) { bcnt[i] = 0; boff[i] = 0; }
    __syncthreads();

    // phase A: count per bucket
    for (int i = t; i < nvec; i += 256) {
        int4 c = col4[i];
        atomicAdd(&bcnt[c.x >> BSH], 1);
        atomicAdd(&bcnt[c.y >> BSH], 1);
        atomicAdd(&bcnt[c.z >> BSH], 1);
        atomicAdd(&bcnt[c.w >> BSH], 1);
    }
    __syncthreads();

    // phase B: exclusive scan of bcnt -> bstart; reserve global runs
    {
        int v = (t < NB) ? bcnt[t] : 0;
        int lane = t & 63, w = t >> 6;
        int s = v;
#pragma unroll
        for (int off = 1; off < 64; off <<= 1) {
            int u = __shfl_up(s, off);
            if (lane >= off) s += u;
        }
        if (lane == 63) wt[w] = s;
        __syncthreads();
        int wo = 0;
        for (int ww = 0; ww < w; ww++) wo += wt[ww];
        if (t < NB) {
            bstart[t] = s - v + wo;
            gbase[t] = (v > 0) ? atomicAdd(&gcursor[t], v) : 0;
        }
    }
    __syncthreads();

    // phase C: place edges into LDS, bucket-sorted; remember bucket id
    for (int i = t; i < nvec; i += 256) {
        int4 c = col4[i];
        int4 r = row4[i];
        int b0 = c.x >> BSH, b1 = c.y >> BSH, b2 = c.z >> BSH, b3 = c.w >> BSH;
        int p0 = bstart[b0] + atomicAdd(&boff[b0], 1);
        int p1 = bstart[b1] + atomicAdd(&boff[b1], 1);
        int p2 = bstart[b2] + atomicAdd(&boff[b2], 1);
        int p3 = bstart[b3] + atomicAdd(&boff[b3], 1);
        stage[p0] = (r.x << BSH) | (c.x & (BNODES - 1)); sbkt[p0] = (unsigned char)b0;
        stage[p1] = (r.y << BSH) | (c.y & (BNODES - 1)); sbkt[p1] = (unsigned char)b1;
        stage[p2] = (r.z << BSH) | (c.z & (BNODES - 1)); sbkt[p2] = (unsigned char)b2;
        stage[p3] = (r.w << BSH) | (c.w & (BNODES - 1)); sbkt[p3] = (unsigned char)b3;
    }
    __syncthreads();

    // phase D: flush runs contiguously (coalesced across the wave)
    for (int i = t; i < nblk; i += 256) {
        int e = stage[i];
        int b = sbkt[i];
        staging[(size_t)b * CAP + gbase[b] + (i - bstart[b])] = e;
    }
}

// ---- level 2: per-quarter CSR build + fused z0; 4 sub-blocks/bucket ----
// Sub-block q of bucket b: reads the bucket segment once; per-node counts
// only for its own 128 nodes (LDS atomics); other quarters' totals via
// ballot+popc (scalar atomics) -> quarter prefix -> csrc base. Scatters
// own quarter; writes rec + zA rows for its 128 nodes.
__global__ __launch_bounds__(256) void k_build(const int* __restrict__ gcursor,
                                               const int* __restrict__ staging,
                                               const float* __restrict__ emb,
                                               int4* __restrict__ rec,
                                               int* __restrict__ csrc,
                                               __half* __restrict__ zA) {
    __shared__ int ldeg[128];
    __shared__ int lcur[128];
    __shared__ int gsc[NB];
    __shared__ int qcnt[4];
    __shared__ int wtt[4];

    int b = blockIdx.x >> 2;
    int q = blockIdx.x & 3;
    int t = threadIdx.x;
    int lane = t & 63, w = t >> 6;
    int n0 = (b << BSH) + (q << 7);   // first node of this quarter
    int cnt = gcursor[b];
    const int* st = staging + (size_t)b * CAP;

    if (t < 128) ldeg[t] = 0;
    if (t < 4) qcnt[t] = 0;

    // bucketStart[b] via in-block exclusive scan of gcursor[0..NB)
    {
        int v = (t < NB) ? gcursor[t] : 0;
        int ss = v;
#pragma unroll
        for (int off = 1; off < 64; off <<= 1) {
            int u = __shfl_up(ss, off);
            if (lane >= off) ss += u;
        }
        if (lane == 63) wtt[w] = ss;
        __syncthreads();
        int wo = 0;
        for (int ww = 0; ww < w; ww++) wo += wtt[ww];
        if (t < NB) gsc[t] = ss - v + wo;
    }
    __syncthreads();

    // count phase: own quarter per-node; all quarters' totals via ballot
    int iters = (cnt + 255) >> 8;
    for (int it = 0; it < iters; it++) {
        int i = it * 256 + t;
        bool valid = i < cnt;
        int e = valid ? st[i] : 0;
        int dl = e & (BNODES - 1);
        int qq = dl >> 7;
#pragma unroll
        for (int z = 0; z < 4; z++) {
            unsigned long long m = __ballot(valid && qq == z);
            if (lane == 0 && m) atomicAdd(&qcnt[z], __popcll(m));
        }
        if (valid && qq == q) atomicAdd(&ldeg[dl & 127], 1);
    }
    __syncthreads();

    // quarter prefix (counts of quarters < q within this bucket)
    int qpre = 0;
    for (int z = 0; z < q; z++) qpre += qcnt[z];

    // scan over own 128 counters (waves 0,1 carry the data)
    int a = (t < 128) ? ldeg[t] : 0;
    int ss = a;
#pragma unroll
    for (int off = 1; off < 64; off <<= 1) {
        int u = __shfl_up(ss, off);
        if (lane >= off) ss += u;
    }
    if (lane == 63) wtt[w] = ss;
    __syncthreads();
    int wo = 0;
    for (int ww = 0; ww < w; ww++) wo += wtt[ww];
    int excl = ss - a + wo;

    if (t < 128) {
        int gb = gsc[b] + qpre + excl;
        lcur[t] = gb;
        int n = n0 + t;
        if (n < N_NODES) {
            float di = (a > 0) ? rsqrtf((float)a) : 0.0f;
            rec[n] = make_int4(gb, a, __float_as_int(di), 0);
        }
    }
    __syncthreads();

    // scatter own quarter into its contiguous csrc range (single owner)
    for (int i = t; i < cnt; i += 256) {
        int e = st[i];
        int dl = e & (BNODES - 1);
        if ((dl >> 7) == q) {
            int p = atomicAdd(&lcur[dl & 127], 1);
            csrc[p] = e >> BSH;
        }
    }

    // fused z0: zA[n] = fp16(emb[n] * dinv[n]) for own 128 nodes
    // 128 nodes x 16 float4-groups = 2048 groups; 8 iterations
    for (int i = t; i < 128 * (DIM / 4); i += 256) {
        int nl = i >> 4;           // local node
        int n = n0 + nl;
        if (n < N_NODES) {
            int d = ldeg[nl];
            float di = (d > 0) ? rsqrtf((float)d) : 0.0f;
            const float4 v = ((const float4*)(emb + (size_t)n * DIM))[i & 15];
            union { ushort h[4]; uint2 u; } pk;
            __half h0 = __float2half(v.x * di);
            __half h1 = __float2half(v.y * di);
            __half h2 = __float2half(v.z * di);
            __half h3 = __float2half(v.w * di);
            pk.h[0] = *(ushort*)&h0; pk.h[1] = *(ushort*)&h1;
            pk.h[2] = *(ushort*)&h2; pk.h[3] = *(ushort*)&h3;
            ((uint2*)(zA + (size_t)n * DIM))[i & 15] = pk.u;
        }
    }
}

// ---- SpMV: one wave per dst node; exact ceil(deg/8) gather groups of 8;
// fp16 rows, packed half2 accumulate; invalid slots -> zero row.
// mode 0: write z_out = x*dinv (fp16) only.
// mode 2: final: out = 0.25*(emb + sqrt(deg)*(z2+z3) + x3); no z write.
__global__ __launch_bounds__(256) void k_spmv(
    const int4* __restrict__ rec, const int* __restrict__ csrc,
    const __half* __restrict__ z, __half* __restrict__ znext,
    const __half* __restrict__ zprev, const float* __restrict__ emb,
    float* __restrict__ out, int mode) {
    int wave = (blockIdx.x * blockDim.x + threadIdx.x) >> 6;
    int lane = threadIdx.x & 63;
    if (wave >= N_NODES) return;
    int g = lane >> 3;   // edge slot within group 0..7
    int l = lane & 7;    // feature chunk: features [l*8, l*8+8)

    int4 nr = rec[wave];          // broadcast load
    int start = nr.x;
    int cnt = nr.y;
    float di = __int_as_float(nr.z);
    int ng = (cnt + 7) >> 3;      // gather groups (wave-uniform)

    __half2 hz = __float2half2_rn(0.0f);
    __half2 hacc0 = hz, hacc1 = hz, hacc2 = hz, hacc3 = hz;

#define GIDX(KK, SV)                                 \
    int e_##SV = (KK) * 8 + g;                       \
    int SV = csrc[start + e_##SV];                   \
    SV = (e_##SV < cnt) ? SV : N_NODES;

#define GFETCH(SV, VV)                               \
    uint4 VV = *((const uint4*)(z + ((size_t)SV << 6)) + l);

#define GADD(VV)                                                          \
    do {                                                                  \
        const __half2* hv = (const __half2*)&VV;                          \
        hacc0 = __hadd2(hacc0, hv[0]);                                    \
        hacc1 = __hadd2(hacc1, hv[1]);                                    \
        hacc2 = __hadd2(hacc2, hv[2]);                                    \
        hacc3 = __hadd2(hacc3, hv[3]);                                    \
    } while (0)

    int k = 0;
    for (; k + 4 <= ng; k += 4) {
        GIDX(k + 0, s0) GIDX(k + 1, s1) GIDX(k + 2, s2) GIDX(k + 3, s3)
        GFETCH(s0, v0) GFETCH(s1, v1) GFETCH(s2, v2) GFETCH(s3, v3)
        GADD(v0); GADD(v1); GADD(v2); GADD(v3);
    }
    int rem = ng - k;           // wave-uniform 0..3
    if (rem > 0) {
        GIDX(k + 0, t0)
        if (rem > 1) {
            GIDX(k + 1, t1)
            if (rem > 2) {
                GIDX(k + 2, t2)
                GFETCH(t0, w0) GFETCH(t1, w1) GFETCH(t2, w2)
                GADD(w0); GADD(w1); GADD(w2);
            } else {
                GFETCH(t0, w0) GFETCH(t1, w1)
                GADD(w0); GADD(w1);
            }
        } else {
            GFETCH(t0, w0)
            GADD(w0);
        }
    }
#undef GIDX
#undef GFETCH
#undef GADD

    // packed reduce across the 8 edge-slot groups (lane bits 3,4,5)
#pragma unroll
    for (int off = 8; off <= 32; off <<= 1) {
        int b0 = __shfl_xor(*(int*)&hacc0, off);
        int b1 = __shfl_xor(*(int*)&hacc1, off);
        int b2 = __shfl_xor(*(int*)&hacc2, off);
        int b3 = __shfl_xor(*(int*)&hacc3, off);
        hacc0 = __hadd2(hacc0, *(__half2*)&b0);
        hacc1 = __hadd2(hacc1, *(__half2*)&b1);
        hacc2 = __hadd2(hacc2, *(__half2*)&b2);
        hacc3 = __hadd2(hacc3, *(__half2*)&b3);
    }

    if (lane < 8) {  // lane == l, holds features [l*8, l*8+8)
        size_t o = (size_t)wave * DIM + lane * 8;
        float x[8];   // x_{k+1} for this node = di * sum
        x[0] = __low2float(hacc0) * di; x[1] = __high2float(hacc0) * di;
        x[2] = __low2float(hacc1) * di; x[3] = __high2float(hacc1) * di;
        x[4] = __low2float(hacc2) * di; x[5] = __high2float(hacc2) * di;
        x[6] = __low2float(hacc3) * di; x[7] = __high2float(hacc3) * di;

        if (mode == 0) {
            union { ushort h[8]; uint4 u; } pk;
#pragma unroll
            for (int j = 0; j < 8; j++) {
                __half hh = __float2half(x[j] * di);
                pk.h[j] = *(ushort*)&hh;
            }
            *((uint4*)(znext + o)) = pk.u;
        } else {
            float sdeg = (cnt > 0) ? sqrtf((float)cnt) : 0.0f;
            uint4 v2 = *((const uint4*)(zprev + o));  // z2 (own row)
            uint4 v3 = *((const uint4*)(z + o));      // z3 (own row)
            const __half2* h2 = (const __half2*)&v2;
            const __half2* h3 = (const __half2*)&v3;
            float4 e0 = ((const float4*)(emb + o))[0];
            float4 e1 = ((const float4*)(emb + o))[1];
            float zs[8];
#pragma unroll
            for (int j = 0; j < 4; j++) {
                float2 a2 = __half22float2(h2[j]);
                float2 a3 = __half22float2(h3[j]);
                zs[2 * j] = a2.x + a3.x;
                zs[2 * j + 1] = a2.y + a3.y;
            }
            float4 o0 = make_float4(
                (e0.x + sdeg * zs[0] + x[0]) * 0.25f,
                (e0.y + sdeg * zs[1] + x[1]) * 0.25f,
                (e0.z + sdeg * zs[2] + x[2]) * 0.25f,
                (e0.w + sdeg * zs[3] + x[3]) * 0.25f);
            float4 o1 = make_float4(
                (e1.x + sdeg * zs[4] + x[4]) * 0.25f,
                (e1.y + sdeg * zs[5] + x[5]) * 0.25f,
                (e1.z + sdeg * zs[6] + x[6]) * 0.25f,
                (e1.w + sdeg * zs[7] + x[7]) * 0.25f);
            ((float4*)(out + o))[0] = o0;
            ((float4*)(out + o))[1] = o1;
        }
    }
}

extern "C" void kernel_launch(void* const* d_in, const int* in_sizes, int n_in,
                              void* d_out, int out_size, void* d_ws, size_t ws_size,
                              hipStream_t stream) {
    const float* emb = (const float*)d_in[0];
    const int* ei = (const int*)d_in[1];  // [2, E]: row = ei[0:E], col = ei[E:2E]
    float* out = (float*)d_out;

    char* ws = (char*)d_ws;
    size_t off = 0;
    auto alloc = [&](size_t bytes) -> void* {
        void* p = ws + off;
        off += (bytes + 511) & ~(size_t)511;
        return p;
    };
    // persistent region
    int4* rec = (int4*)alloc((size_t)N_NODES * 16);
    int* gcursor = (int*)alloc(NB * 4);
    int* csrc = (int*)alloc(((size_t)N_EDGES + 64) * 4);  // +64 overread slack
    // z buffers have N_NODES+1 rows; row N_NODES is the zero row.
    // zB overlays staging (staging dead before zB is first written, pass 1).
    size_t zbytes = (size_t)(N_NODES + 1) * DIM * 2;  // 12.81 MB
    size_t stbytes = (size_t)NB * CAP * 4;            // 16.05 MB
    char* transient = (char*)alloc(stbytes > zbytes ? stbytes : zbytes);
    int* staging = (int*)transient;
    __half* zB = (__half*)transient;
    __half* zA = (__half*)alloc(zbytes);              // standalone (k_build writes it)

    hipMemsetAsync(gcursor, 0, NB * 4, stream);
    hipMemsetAsync(zA + (size_t)N_NODES * DIM, 0, DIM * 2, stream);  // zA zero row

    k_bucket<<<NBLK1, 256, 0, stream>>>(ei, gcursor, staging);
    k_build<<<NB * 4, 256, 0, stream>>>(gcursor, staging, emb, rec, csrc, zA);
    // staging dead from here; zB overlays it.
    hipMemsetAsync(zB + (size_t)N_NODES * DIM, 0, DIM * 2, stream);  // zB zero row

    int spmvBlocks = (N_NODES + 3) / 4;  // 4 waves/block, 1 wave/node
    // pass1: zA -> zB (z2); pass2: zB -> zA (z3); pass3: gathers zA, reads
    // zB(z2)+zA(z3) own rows, writes out.
    k_spmv<<<spmvBlocks, 256, 0, stream>>>(rec, csrc, zA, zB, nullptr, emb, out, 0);
    k_spmv<<<spmvBlocks, 256, 0, stream>>>(rec, csrc, zB, zA, nullptr, emb, out, 0);
    k_spmv<<<spmvBlocks, 256, 0, stream>>>(rec, csrc, zA, nullptr, zB, emb, out, 2);
}

// Round 12
// 306.722 us; speedup vs baseline: 1.0990x; 1.0990x over previous
//
#include <hip/hip_runtime.h>
#include <hip/hip_bf16.h>
#include <hip/hip_fp16.h>
#include <stdint.h>

// LightGCN on MI355X, round 15 (= exact restore of R9, the measured best:
// 307.9us).
// R14 post-mortem: z0 fusion into k_build regressed (k_build 91us: 110MB
// at 1.2 TB/s — 29% occupancy + ballot convergence made fused streaming
// ~3x more expensive than standalone k_z0). Session probes established:
// - spmv 58.8us x3: FETCH pinned 182MB ~ 8-XCD compulsory floor
//   (write-insensitive R9, depth-insensitive R10, VALU-insensitive
//   R7/R10) -> TCC<->L3 random-line service bound.
// - k_bucket ~50us: LDS-atomic throughput (replication null R13).
// - k_build: R9's redundant-read 4-sub-block form beats all "lean"
//   alternatives tried (R11/R12 staging-run-length refuted, R14 fusion
//   regressed).
// R15 = R9 verbatim: NB=196/CHUNK=8192 bucket sort; 4 sub-blocks/bucket
// build; standalone k_z0 (zero rows in tail); spmv exact ceil(deg/8)
// groups, fp16 rows, z-only intermediate writes, fused final epilogue.

#define N_NODES 100000
#define N_EDGES 3200000
#define DIM 64

#define BSH 9                // 512 nodes per bucket
#define BNODES 512
#define NB 196               // ceil(100000/512)
#define CAP 20480            // staging slots per bucket (mean 16327)

#define CHUNK 8192           // edges per k_bucket block
#define NBLK1 ((N_EDGES + CHUNK - 1) / CHUNK)  // 391

// ---- level 1: bucket edges by dst range (dst>>9) ----
__global__ __launch_bounds__(256) void k_bucket(const int* __restrict__ ei,
                                                int* __restrict__ gcursor,
                                                int* __restrict__ staging) {
    __shared__ int stage[CHUNK];            // packed (row<<9)|dstLocal
    __shared__ unsigned char sbkt[CHUNK];   // bucket id per staged entry
    __shared__ int bcnt[NB];
    __shared__ int boff[NB];
    __shared__ int bstart[NB];
    __shared__ int gbase[NB];
    __shared__ int wt[4];

    int t = threadIdx.x;
    int e0 = blockIdx.x * CHUNK;
    int nblk = min(CHUNK, N_EDGES - e0);
    int nvec = nblk >> 2;

    const int4* col4 = (const int4*)(ei + N_EDGES + e0);
    const int4* row4 = (const int4*)(ei + e0);

    for (int i = t; i < NB; i += 256) { bcnt[i] = 0; boff[i] = 0; }
    __syncthreads();

    // phase A: count per bucket
    for (int i = t; i < nvec; i += 256) {
        int4 c = col4[i];
        atomicAdd(&bcnt[c.x >> BSH], 1);
        atomicAdd(&bcnt[c.y >> BSH], 1);
        atomicAdd(&bcnt[c.z >> BSH], 1);
        atomicAdd(&bcnt[c.w >> BSH], 1);
    }
    __syncthreads();

    // phase B: exclusive scan of bcnt -> bstart; reserve global runs
    {
        int v = (t < NB) ? bcnt[t] : 0;
        int lane = t & 63, w = t >> 6;
        int s = v;
#pragma unroll
        for (int off = 1; off < 64; off <<= 1) {
            int u = __shfl_up(s, off);
            if (lane >= off) s += u;
        }
        if (lane == 63) wt[w] = s;
        __syncthreads();
        int wo = 0;
        for (int ww = 0; ww < w; ww++) wo += wt[ww];
        if (t < NB) {
            bstart[t] = s - v + wo;
            gbase[t] = (v > 0) ? atomicAdd(&gcursor[t], v) : 0;
        }
    }
    __syncthreads();

    // phase C: place edges into LDS, bucket-sorted; remember bucket id
    for (int i = t; i < nvec; i += 256) {
        int4 c = col4[i];
        int4 r = row4[i];
        int b0 = c.x >> BSH, b1 = c.y >> BSH, b2 = c.z >> BSH, b3 = c.w >> BSH;
        int p0 = bstart[b0] + atomicAdd(&boff[b0], 1);
        int p1 = bstart[b1] + atomicAdd(&boff[b1], 1);
        int p2 = bstart[b2] + atomicAdd(&boff[b2], 1);
        int p3 = bstart[b3] + atomicAdd(&boff[b3], 1);
        stage[p0] = (r.x << BSH) | (c.x & (BNODES - 1)); sbkt[p0] = (unsigned char)b0;
        stage[p1] = (r.y << BSH) | (c.y & (BNODES - 1)); sbkt[p1] = (unsigned char)b1;
        stage[p2] = (r.z << BSH) | (c.z & (BNODES - 1)); sbkt[p2] = (unsigned char)b2;
        stage[p3] = (r.w << BSH) | (c.w & (BNODES - 1)); sbkt[p3] = (unsigned char)b3;
    }
    __syncthreads();

    // phase D: flush runs contiguously (coalesced across the wave)
    for (int i = t; i < nblk; i += 256) {
        int e = stage[i];
        int b = sbkt[i];
        staging[(size_t)b * CAP + gbase[b] + (i - bstart[b])] = e;
    }
}

// ---- level 2: per-bucket CSR build; 4 sub-blocks per bucket ----
// Each sub-block: scans gcursor (bucketStart), counts ALL 512 nodes in LDS
// (redundant across the 4), scatters only its 128-node quarter into the
// quarter's contiguous csrc sub-range.
__global__ __launch_bounds__(256) void k_build(const int* __restrict__ gcursor,
                                               const int* __restrict__ staging,
                                               int4* __restrict__ rec,
                                               float* __restrict__ dinv,
                                               int* __restrict__ csrc) {
    __shared__ int ldeg[BNODES];
    __shared__ int lcur[BNODES];
    __shared__ int gsc[NB];
    __shared__ int wtt[4];

    int b = blockIdx.x >> 2;
    int q = blockIdx.x & 3;
    int t = threadIdx.x;
    int n0 = b << BSH;
    int nloc = min(BNODES, N_NODES - n0);
    int cnt = gcursor[b];
    const int* st = staging + (size_t)b * CAP;

    // bucketStart[b] via in-block exclusive scan of gcursor[0..NB)
    {
        int v = (t < NB) ? gcursor[t] : 0;
        int lane = t & 63, w = t >> 6;
        int ss = v;
#pragma unroll
        for (int off = 1; off < 64; off <<= 1) {
            int u = __shfl_up(ss, off);
            if (lane >= off) ss += u;
        }
        if (lane == 63) wtt[w] = ss;
        ldeg[t] = 0; ldeg[t + 256] = 0;
        __syncthreads();
        int wo = 0;
        for (int ww = 0; ww < w; ww++) wo += wtt[ww];
        if (t < NB) gsc[t] = ss - v + wo;
    }
    __syncthreads();
    int bstartB = gsc[b];

    // count ALL nodes of the bucket (each sub-block redundantly)
    for (int i = t; i < cnt; i += 256) {
        atomicAdd(&ldeg[st[i] & (BNODES - 1)], 1);
    }
    __syncthreads();

    // block scan over 512 counters (2 per thread)
    int a0 = ldeg[2 * t], a1 = ldeg[2 * t + 1];
    int s = a0 + a1;
    int lane = t & 63, w = t >> 6;
    int ss = s;
#pragma unroll
    for (int off = 1; off < 64; off <<= 1) {
        int u = __shfl_up(ss, off);
        if (lane >= off) ss += u;
    }
    if (lane == 63) wtt[w] = ss;
    __syncthreads();
    int wo = 0;
    for (int ww = 0; ww < w; ww++) wo += wtt[ww];
    int excl = ss - s + wo;

    int gb = bstartB + excl;
    int n = n0 + 2 * t;
    lcur[2 * t] = gb;
    lcur[2 * t + 1] = gb + a0;
    // nodes 2t and 2t+1 are always in the same 128-quarter (2t even)
    if (((2 * t) >> 7) == q) {
        if (2 * t < nloc) {
            float di = (a0 > 0) ? rsqrtf((float)a0) : 0.0f;
            rec[n] = make_int4(gb, a0, __float_as_int(di), 0);
            dinv[n] = di;
        }
        if (2 * t + 1 < nloc) {
            float di = (a1 > 0) ? rsqrtf((float)a1) : 0.0f;
            rec[n + 1] = make_int4(gb + a0, a1, __float_as_int(di), 0);
            dinv[n + 1] = di;
        }
    }
    __syncthreads();

    // scatter only this quarter's nodes (contiguous csrc sub-range,
    // single owner -> L2 write combining)
    for (int i = t; i < cnt; i += 256) {
        int e = st[i];
        int dl = e & (BNODES - 1);
        if ((dl >> 7) == q) {
            int p = atomicAdd(&lcur[dl], 1);
            csrc[p] = e >> BSH;
        }
    }
}

// z0 = fp16(emb * dinv[node]); tail threads zero the zero rows of zA/zB
__global__ void k_z0(const float* __restrict__ emb, const float* __restrict__ dinv,
                     __half* __restrict__ zA, __half* __restrict__ zB) {
    const int total = (N_NODES * DIM) / 4;  // 1.6M groups of 4
    int i = blockIdx.x * blockDim.x + threadIdx.x;
    if (i >= total) {
        int r = i - total;
        if (r < 16) ((uint2*)(zA + (size_t)N_NODES * DIM))[r] = make_uint2(0, 0);
        else if (r < 32) ((uint2*)(zB + (size_t)N_NODES * DIM))[r - 16] = make_uint2(0, 0);
        return;
    }
    float di = dinv[(i * 4) >> 6];
    const float4 v = ((const float4*)emb)[i];
    union { ushort h[4]; uint2 u; } pk;
    __half h0 = __float2half(v.x * di);
    __half h1 = __float2half(v.y * di);
    __half h2 = __float2half(v.z * di);
    __half h3 = __float2half(v.w * di);
    pk.h[0] = *(ushort*)&h0; pk.h[1] = *(ushort*)&h1;
    pk.h[2] = *(ushort*)&h2; pk.h[3] = *(ushort*)&h3;
    ((uint2*)zA)[i] = pk.u;
}

// ---- SpMV: one wave per dst node; exact ceil(deg/8) gather groups of 8;
// fp16 rows, packed half2 accumulate; invalid slots -> zero row.
// mode 0: write z_out = x*dinv (fp16) only.
// mode 2: final: out = 0.25*(emb + sqrt(deg)*(z2+z3) + x3); no z write.
__global__ __launch_bounds__(256) void k_spmv(
    const int4* __restrict__ rec, const int* __restrict__ csrc,
    const __half* __restrict__ z, __half* __restrict__ znext,
    const __half* __restrict__ zprev, const float* __restrict__ emb,
    float* __restrict__ out, int mode) {
    int wave = (blockIdx.x * blockDim.x + threadIdx.x) >> 6;
    int lane = threadIdx.x & 63;
    if (wave >= N_NODES) return;
    int g = lane >> 3;   // edge slot within group 0..7
    int l = lane & 7;    // feature chunk: features [l*8, l*8+8)

    int4 nr = rec[wave];          // broadcast load
    int start = nr.x;
    int cnt = nr.y;
    float di = __int_as_float(nr.z);
    int ng = (cnt + 7) >> 3;      // gather groups (wave-uniform)

    __half2 hz = __float2half2_rn(0.0f);
    __half2 hacc0 = hz, hacc1 = hz, hacc2 = hz, hacc3 = hz;

#define GIDX(KK, SV)                                 \
    int e_##SV = (KK) * 8 + g;                       \
    int SV = csrc[start + e_##SV];                   \
    SV = (e_##SV < cnt) ? SV : N_NODES;

#define GFETCH(SV, VV)                               \
    uint4 VV = *((const uint4*)(z + ((size_t)SV << 6)) + l);

#define GADD(VV)                                                          \
    do {                                                                  \
        const __half2* hv = (const __half2*)&VV;                          \
        hacc0 = __hadd2(hacc0, hv[0]);                                    \
        hacc1 = __hadd2(hacc1, hv[1]);                                    \
        hacc2 = __hadd2(hacc2, hv[2]);                                    \
        hacc3 = __hadd2(hacc3, hv[3]);                                    \
    } while (0)

    int k = 0;
    for (; k + 4 <= ng; k += 4) {
        GIDX(k + 0, s0) GIDX(k + 1, s1) GIDX(k + 2, s2) GIDX(k + 3, s3)
        GFETCH(s0, v0) GFETCH(s1, v1) GFETCH(s2, v2) GFETCH(s3, v3)
        GADD(v0); GADD(v1); GADD(v2); GADD(v3);
    }
    int rem = ng - k;           // wave-uniform 0..3
    if (rem > 0) {
        GIDX(k + 0, t0)
        if (rem > 1) {
            GIDX(k + 1, t1)
            if (rem > 2) {
                GIDX(k + 2, t2)
                GFETCH(t0, w0) GFETCH(t1, w1) GFETCH(t2, w2)
                GADD(w0); GADD(w1); GADD(w2);
            } else {
                GFETCH(t0, w0) GFETCH(t1, w1)
                GADD(w0); GADD(w1);
            }
        } else {
            GFETCH(t0, w0)
            GADD(w0);
        }
    }
#undef GIDX
#undef GFETCH
#undef GADD

    // packed reduce across the 8 edge-slot groups (lane bits 3,4,5)
#pragma unroll
    for (int off = 8; off <= 32; off <<= 1) {
        int b0 = __shfl_xor(*(int*)&hacc0, off);
        int b1 = __shfl_xor(*(int*)&hacc1, off);
        int b2 = __shfl_xor(*(int*)&hacc2, off);
        int b3 = __shfl_xor(*(int*)&hacc3, off);
        hacc0 = __hadd2(hacc0, *(__half2*)&b0);
        hacc1 = __hadd2(hacc1, *(__half2*)&b1);
        hacc2 = __hadd2(hacc2, *(__half2*)&b2);
        hacc3 = __hadd2(hacc3, *(__half2*)&b3);
    }

    if (lane < 8) {  // lane == l, holds features [l*8, l*8+8)
        size_t o = (size_t)wave * DIM + lane * 8;
        float x[8];   // x_{k+1} for this node = di * sum
        x[0] = __low2float(hacc0) * di; x[1] = __high2float(hacc0) * di;
        x[2] = __low2float(hacc1) * di; x[3] = __high2float(hacc1) * di;
        x[4] = __low2float(hacc2) * di; x[5] = __high2float(hacc2) * di;
        x[6] = __low2float(hacc3) * di; x[7] = __high2float(hacc3) * di;

        if (mode == 0) {
            union { ushort h[8]; uint4 u; } pk;
#pragma unroll
            for (int j = 0; j < 8; j++) {
                __half hh = __float2half(x[j] * di);
                pk.h[j] = *(ushort*)&hh;
            }
            *((uint4*)(znext + o)) = pk.u;
        } else {
            float sdeg = (cnt > 0) ? sqrtf((float)cnt) : 0.0f;
            uint4 v2 = *((const uint4*)(zprev + o));  // z2 (own row)
            uint4 v3 = *((const uint4*)(z + o));      // z3 (own row)
            const __half2* h2 = (const __half2*)&v2;
            const __half2* h3 = (const __half2*)&v3;
            float4 e0 = ((const float4*)(emb + o))[0];
            float4 e1 = ((const float4*)(emb + o))[1];
            float zs[8];
#pragma unroll
            for (int j = 0; j < 4; j++) {
                float2 a2 = __half22float2(h2[j]);
                float2 a3 = __half22float2(h3[j]);
                zs[2 * j] = a2.x + a3.x;
                zs[2 * j + 1] = a2.y + a3.y;
            }
            float4 o0 = make_float4(
                (e0.x + sdeg * zs[0] + x[0]) * 0.25f,
                (e0.y + sdeg * zs[1] + x[1]) * 0.25f,
                (e0.z + sdeg * zs[2] + x[2]) * 0.25f,
                (e0.w + sdeg * zs[3] + x[3]) * 0.25f);
            float4 o1 = make_float4(
                (e1.x + sdeg * zs[4] + x[4]) * 0.25f,
                (e1.y + sdeg * zs[5] + x[5]) * 0.25f,
                (e1.z + sdeg * zs[6] + x[6]) * 0.25f,
                (e1.w + sdeg * zs[7] + x[7]) * 0.25f);
            ((float4*)(out + o))[0] = o0;
            ((float4*)(out + o))[1] = o1;
        }
    }
}

extern "C" void kernel_launch(void* const* d_in, const int* in_sizes, int n_in,
                              void* d_out, int out_size, void* d_ws, size_t ws_size,
                              hipStream_t stream) {
    const float* emb = (const float*)d_in[0];
    const int* ei = (const int*)d_in[1];  // [2, E]: row = ei[0:E], col = ei[E:2E]
    float* out = (float*)d_out;

    char* ws = (char*)d_ws;
    size_t off = 0;
    auto alloc = [&](size_t bytes) -> void* {
        void* p = ws + off;
        off += (bytes + 511) & ~(size_t)511;
        return p;
    };
    // persistent region
    int4* rec = (int4*)alloc((size_t)N_NODES * 16);
    float* dinv = (float*)alloc((size_t)N_NODES * 4);
    int* gcursor = (int*)alloc(NB * 4);
    int* csrc = (int*)alloc(((size_t)N_EDGES + 64) * 4);  // +64 overread slack
    // transient union: staging (16MB) dead after k_build; zA overlays it.
    // z buffers have N_NODES+1 rows; row N_NODES is the zero row.
    size_t zbytes = (size_t)(N_NODES + 1) * DIM * 2;  // 12.81 MB
    size_t stbytes = (size_t)NB * CAP * 4;            // 16.05 MB
    char* transient = (char*)alloc(stbytes > zbytes ? stbytes : zbytes);
    int* staging = (int*)transient;
    __half* zA = (__half*)transient;
    __half* zB = (__half*)alloc(zbytes);

    hipMemsetAsync(gcursor, 0, NB * 4, stream);

    k_bucket<<<NBLK1, 256, 0, stream>>>(ei, gcursor, staging);
    k_build<<<NB * 4, 256, 0, stream>>>(gcursor, staging, rec, dinv, csrc);
    // staging dead from here; zA overlays it. Tail threads zero zero-rows.
    k_z0<<<(N_NODES * DIM / 4) / 256 + 1, 256, 0, stream>>>(emb, dinv, zA, zB);

    int spmvBlocks = (N_NODES + 3) / 4;  // 4 waves/block, 1 wave/node
    // pass1: zA -> zB (z2); pass2: zB -> zA (z3); pass3: gathers zA, reads
    // zB(z2)+zA(z3) own rows, writes out.
    k_spmv<<<spmvBlocks, 256, 0, stream>>>(rec, csrc, zA, zB, nullptr, emb, out, 0);
    k_spmv<<<spmvBlocks, 256, 0, stream>>>(rec, csrc, zB, zA, nullptr, emb, out, 0);
    k_spmv<<<spmvBlocks, 256, 0, stream>>>(rec, csrc, zA, nullptr, zB, emb, out, 2);
}

// Round 13
// 284.269 us; speedup vs baseline: 1.1858x; 1.0790x over previous
//
#include <hip/hip_runtime.h>
#include <hip/hip_bf16.h>
#include <hip/hip_fp16.h>
#include <stdint.h>

// LightGCN on MI355X, round 16.
// R15 confirmed 306.7us (R9 structure). spmv x3 @58.6 = 176us (probed
// floor: write-insensitive R9, depth-insensitive R10, VALU-insensitive
// R7/R10 -> TCC/L3 random-line service bound, FETCH pinned 182MB).
// Prep ~130us is NOT at a floor. Two TLP edits, one variable per kernel:
// (1) k_build: 196 blocks x 1024 threads (was 784x256). Same total waves
//     (3136) as R9 but NO redundancy: count 3.2M atomics (was 12.8M),
//     staging read 12.8MB once (was 51MB), scatter once. R5->R9 showed
//     latency-hiding was k_build's binding constraint; this keeps it
//     while deleting the redundant work.
// (2) k_bucket: 512 threads/block (was 256). LDS 41KB still caps at 3
//     blocks/CU, so waves/CU double 12->24 — double latency hiding for
//     the LDS-atomic chains at zero extra work (VALUBusy 2.5% = pure
//     latency exposure).
// spmv/k_z0 = R15 verbatim.

#define N_NODES 100000
#define N_EDGES 3200000
#define DIM 64

#define BSH 9                // 512 nodes per bucket
#define BNODES 512
#define NB 196               // ceil(100000/512)
#define CAP 20480            // staging slots per bucket (mean 16327)

#define CHUNK 8192           // edges per k_bucket block
#define NBLK1 ((N_EDGES + CHUNK - 1) / CHUNK)  // 391

// ---- level 1: bucket edges by dst range (dst>>9); 512 threads ----
__global__ __launch_bounds__(512) void k_bucket(const int* __restrict__ ei,
                                                int* __restrict__ gcursor,
                                                int* __restrict__ staging) {
    __shared__ int stage[CHUNK];            // packed (row<<9)|dstLocal
    __shared__ unsigned char sbkt[CHUNK];   // bucket id per staged entry
    __shared__ int bcnt[NB];
    __shared__ int boff[NB];
    __shared__ int bstart[NB];
    __shared__ int gbase[NB];
    __shared__ int wt[8];

    int t = threadIdx.x;
    int e0 = blockIdx.x * CHUNK;
    int nblk = min(CHUNK, N_EDGES - e0);
    int nvec = nblk >> 2;

    const int4* col4 = (const int4*)(ei + N_EDGES + e0);
    const int4* row4 = (const int4*)(ei + e0);

    for (int i = t; i < NB; i += 512) { bcnt[i] = 0; boff[i] = 0; }
    __syncthreads();

    // phase A: count per bucket
    for (int i = t; i < nvec; i += 512) {
        int4 c = col4[i];
        atomicAdd(&bcnt[c.x >> BSH], 1);
        atomicAdd(&bcnt[c.y >> BSH], 1);
        atomicAdd(&bcnt[c.z >> BSH], 1);
        atomicAdd(&bcnt[c.w >> BSH], 1);
    }
    __syncthreads();

    // phase B: exclusive scan of bcnt -> bstart; reserve global runs
    {
        int v = (t < NB) ? bcnt[t] : 0;
        int lane = t & 63, w = t >> 6;
        int s = v;
#pragma unroll
        for (int off = 1; off < 64; off <<= 1) {
            int u = __shfl_up(s, off);
            if (lane >= off) s += u;
        }
        if (lane == 63) wt[w] = s;
        __syncthreads();
        int wo = 0;
        for (int ww = 0; ww < w; ww++) wo += wt[ww];
        if (t < NB) {
            bstart[t] = s - v + wo;
            gbase[t] = (v > 0) ? atomicAdd(&gcursor[t], v) : 0;
        }
    }
    __syncthreads();

    // phase C: place edges into LDS, bucket-sorted; remember bucket id
    for (int i = t; i < nvec; i += 512) {
        int4 c = col4[i];
        int4 r = row4[i];
        int b0 = c.x >> BSH, b1 = c.y >> BSH, b2 = c.z >> BSH, b3 = c.w >> BSH;
        int p0 = bstart[b0] + atomicAdd(&boff[b0], 1);
        int p1 = bstart[b1] + atomicAdd(&boff[b1], 1);
        int p2 = bstart[b2] + atomicAdd(&boff[b2], 1);
        int p3 = bstart[b3] + atomicAdd(&boff[b3], 1);
        stage[p0] = (r.x << BSH) | (c.x & (BNODES - 1)); sbkt[p0] = (unsigned char)b0;
        stage[p1] = (r.y << BSH) | (c.y & (BNODES - 1)); sbkt[p1] = (unsigned char)b1;
        stage[p2] = (r.z << BSH) | (c.z & (BNODES - 1)); sbkt[p2] = (unsigned char)b2;
        stage[p3] = (r.w << BSH) | (c.w & (BNODES - 1)); sbkt[p3] = (unsigned char)b3;
    }
    __syncthreads();

    // phase D: flush runs contiguously (coalesced across the wave)
    for (int i = t; i < nblk; i += 512) {
        int e = stage[i];
        int b = sbkt[i];
        staging[(size_t)b * CAP + gbase[b] + (i - bstart[b])] = e;
    }
}

// ---- level 2: CSR build; ONE block of 1024 threads per bucket ----
// Reads the bucket segment once; counts 512 nodes (3.2M total atomics);
// scans; scatters into the bucket's contiguous csrc range (single owner).
__global__ __launch_bounds__(1024) void k_build(const int* __restrict__ gcursor,
                                                const int* __restrict__ staging,
                                                int4* __restrict__ rec,
                                                float* __restrict__ dinv,
                                                int* __restrict__ csrc) {
    __shared__ int ldeg[BNODES];
    __shared__ int lcur[BNODES];
    __shared__ int gsc[NB];
    __shared__ int wtt[16];

    int b = blockIdx.x;
    int t = threadIdx.x;
    int lane = t & 63, w = t >> 6;
    int n0 = b << BSH;
    int nloc = min(BNODES, N_NODES - n0);
    int cnt = gcursor[b];
    const int* st = staging + (size_t)b * CAP;

    if (t < BNODES) ldeg[t] = 0;

    // bucketStart[b] via in-block exclusive scan of gcursor[0..NB)
    {
        int v = (t < NB) ? gcursor[t] : 0;
        int ss = v;
#pragma unroll
        for (int off = 1; off < 64; off <<= 1) {
            int u = __shfl_up(ss, off);
            if (lane >= off) ss += u;
        }
        if (lane == 63) wtt[w] = ss;
        __syncthreads();
        int wo = 0;
        for (int ww = 0; ww < w; ww++) wo += wtt[ww];
        if (t < NB) gsc[t] = ss - v + wo;
    }
    __syncthreads();
    int bstartB = gsc[b];

    // count the bucket's 512 nodes (single pass, no redundancy)
    for (int i = t; i < cnt; i += 1024) {
        atomicAdd(&ldeg[st[i] & (BNODES - 1)], 1);
    }
    __syncthreads();

    // scan over 512 counters (1 per thread, threads 0..511 over 8 waves)
    int a = (t < BNODES) ? ldeg[t] : 0;
    int ss = a;
#pragma unroll
    for (int off = 1; off < 64; off <<= 1) {
        int u = __shfl_up(ss, off);
        if (lane >= off) ss += u;
    }
    if (lane == 63) wtt[w] = ss;
    __syncthreads();
    int wo = 0;
    for (int ww = 0; ww < w; ww++) wo += wtt[ww];
    int excl = ss - a + wo;

    if (t < BNODES) {
        int gb = bstartB + excl;
        lcur[t] = gb;
        if (t < nloc) {
            int n = n0 + t;
            float di = (a > 0) ? rsqrtf((float)a) : 0.0f;
            rec[n] = make_int4(gb, a, __float_as_int(di), 0);
            dinv[n] = di;
        }
    }
    __syncthreads();

    // scatter into this bucket's csrc range (single owner -> L2 combining)
    for (int i = t; i < cnt; i += 1024) {
        int e = st[i];
        int p = atomicAdd(&lcur[e & (BNODES - 1)], 1);
        csrc[p] = e >> BSH;
    }
}

// z0 = fp16(emb * dinv[node]); tail threads zero the zero rows of zA/zB
__global__ void k_z0(const float* __restrict__ emb, const float* __restrict__ dinv,
                     __half* __restrict__ zA, __half* __restrict__ zB) {
    const int total = (N_NODES * DIM) / 4;  // 1.6M groups of 4
    int i = blockIdx.x * blockDim.x + threadIdx.x;
    if (i >= total) {
        int r = i - total;
        if (r < 16) ((uint2*)(zA + (size_t)N_NODES * DIM))[r] = make_uint2(0, 0);
        else if (r < 32) ((uint2*)(zB + (size_t)N_NODES * DIM))[r - 16] = make_uint2(0, 0);
        return;
    }
    float di = dinv[(i * 4) >> 6];
    const float4 v = ((const float4*)emb)[i];
    union { ushort h[4]; uint2 u; } pk;
    __half h0 = __float2half(v.x * di);
    __half h1 = __float2half(v.y * di);
    __half h2 = __float2half(v.z * di);
    __half h3 = __float2half(v.w * di);
    pk.h[0] = *(ushort*)&h0; pk.h[1] = *(ushort*)&h1;
    pk.h[2] = *(ushort*)&h2; pk.h[3] = *(ushort*)&h3;
    ((uint2*)zA)[i] = pk.u;
}

// ---- SpMV: one wave per dst node; exact ceil(deg/8) gather groups of 8;
// fp16 rows, packed half2 accumulate; invalid slots -> zero row.
// mode 0: write z_out = x*dinv (fp16) only.
// mode 2: final: out = 0.25*(emb + sqrt(deg)*(z2+z3) + x3); no z write.
__global__ __launch_bounds__(256) void k_spmv(
    const int4* __restrict__ rec, const int* __restrict__ csrc,
    const __half* __restrict__ z, __half* __restrict__ znext,
    const __half* __restrict__ zprev, const float* __restrict__ emb,
    float* __restrict__ out, int mode) {
    int wave = (blockIdx.x * blockDim.x + threadIdx.x) >> 6;
    int lane = threadIdx.x & 63;
    if (wave >= N_NODES) return;
    int g = lane >> 3;   // edge slot within group 0..7
    int l = lane & 7;    // feature chunk: features [l*8, l*8+8)

    int4 nr = rec[wave];          // broadcast load
    int start = nr.x;
    int cnt = nr.y;
    float di = __int_as_float(nr.z);
    int ng = (cnt + 7) >> 3;      // gather groups (wave-uniform)

    __half2 hz = __float2half2_rn(0.0f);
    __half2 hacc0 = hz, hacc1 = hz, hacc2 = hz, hacc3 = hz;

#define GIDX(KK, SV)                                 \
    int e_##SV = (KK) * 8 + g;                       \
    int SV = csrc[start + e_##SV];                   \
    SV = (e_##SV < cnt) ? SV : N_NODES;

#define GFETCH(SV, VV)                               \
    uint4 VV = *((const uint4*)(z + ((size_t)SV << 6)) + l);

#define GADD(VV)                                                          \
    do {                                                                  \
        const __half2* hv = (const __half2*)&VV;                          \
        hacc0 = __hadd2(hacc0, hv[0]);                                    \
        hacc1 = __hadd2(hacc1, hv[1]);                                    \
        hacc2 = __hadd2(hacc2, hv[2]);                                    \
        hacc3 = __hadd2(hacc3, hv[3]);                                    \
    } while (0)

    int k = 0;
    for (; k + 4 <= ng; k += 4) {
        GIDX(k + 0, s0) GIDX(k + 1, s1) GIDX(k + 2, s2) GIDX(k + 3, s3)
        GFETCH(s0, v0) GFETCH(s1, v1) GFETCH(s2, v2) GFETCH(s3, v3)
        GADD(v0); GADD(v1); GADD(v2); GADD(v3);
    }
    int rem = ng - k;           // wave-uniform 0..3
    if (rem > 0) {
        GIDX(k + 0, t0)
        if (rem > 1) {
            GIDX(k + 1, t1)
            if (rem > 2) {
                GIDX(k + 2, t2)
                GFETCH(t0, w0) GFETCH(t1, w1) GFETCH(t2, w2)
                GADD(w0); GADD(w1); GADD(w2);
            } else {
                GFETCH(t0, w0) GFETCH(t1, w1)
                GADD(w0); GADD(w1);
            }
        } else {
            GFETCH(t0, w0)
            GADD(w0);
        }
    }
#undef GIDX
#undef GFETCH
#undef GADD

    // packed reduce across the 8 edge-slot groups (lane bits 3,4,5)
#pragma unroll
    for (int off = 8; off <= 32; off <<= 1) {
        int b0 = __shfl_xor(*(int*)&hacc0, off);
        int b1 = __shfl_xor(*(int*)&hacc1, off);
        int b2 = __shfl_xor(*(int*)&hacc2, off);
        int b3 = __shfl_xor(*(int*)&hacc3, off);
        hacc0 = __hadd2(hacc0, *(__half2*)&b0);
        hacc1 = __hadd2(hacc1, *(__half2*)&b1);
        hacc2 = __hadd2(hacc2, *(__half2*)&b2);
        hacc3 = __hadd2(hacc3, *(__half2*)&b3);
    }

    if (lane < 8) {  // lane == l, holds features [l*8, l*8+8)
        size_t o = (size_t)wave * DIM + lane * 8;
        float x[8];   // x_{k+1} for this node = di * sum
        x[0] = __low2float(hacc0) * di; x[1] = __high2float(hacc0) * di;
        x[2] = __low2float(hacc1) * di; x[3] = __high2float(hacc1) * di;
        x[4] = __low2float(hacc2) * di; x[5] = __high2float(hacc2) * di;
        x[6] = __low2float(hacc3) * di; x[7] = __high2float(hacc3) * di;

        if (mode == 0) {
            union { ushort h[8]; uint4 u; } pk;
#pragma unroll
            for (int j = 0; j < 8; j++) {
                __half hh = __float2half(x[j] * di);
                pk.h[j] = *(ushort*)&hh;
            }
            *((uint4*)(znext + o)) = pk.u;
        } else {
            float sdeg = (cnt > 0) ? sqrtf((float)cnt) : 0.0f;
            uint4 v2 = *((const uint4*)(zprev + o));  // z2 (own row)
            uint4 v3 = *((const uint4*)(z + o));      // z3 (own row)
            const __half2* h2 = (const __half2*)&v2;
            const __half2* h3 = (const __half2*)&v3;
            float4 e0 = ((const float4*)(emb + o))[0];
            float4 e1 = ((const float4*)(emb + o))[1];
            float zs[8];
#pragma unroll
            for (int j = 0; j < 4; j++) {
                float2 a2 = __half22float2(h2[j]);
                float2 a3 = __half22float2(h3[j]);
                zs[2 * j] = a2.x + a3.x;
                zs[2 * j + 1] = a2.y + a3.y;
            }
            float4 o0 = make_float4(
                (e0.x + sdeg * zs[0] + x[0]) * 0.25f,
                (e0.y + sdeg * zs[1] + x[1]) * 0.25f,
                (e0.z + sdeg * zs[2] + x[2]) * 0.25f,
                (e0.w + sdeg * zs[3] + x[3]) * 0.25f);
            float4 o1 = make_float4(
                (e1.x + sdeg * zs[4] + x[4]) * 0.25f,
                (e1.y + sdeg * zs[5] + x[5]) * 0.25f,
                (e1.z + sdeg * zs[6] + x[6]) * 0.25f,
                (e1.w + sdeg * zs[7] + x[7]) * 0.25f);
            ((float4*)(out + o))[0] = o0;
            ((float4*)(out + o))[1] = o1;
        }
    }
}

extern "C" void kernel_launch(void* const* d_in, const int* in_sizes, int n_in,
                              void* d_out, int out_size, void* d_ws, size_t ws_size,
                              hipStream_t stream) {
    const float* emb = (const float*)d_in[0];
    const int* ei = (const int*)d_in[1];  // [2, E]: row = ei[0:E], col = ei[E:2E]
    float* out = (float*)d_out;

    char* ws = (char*)d_ws;
    size_t off = 0;
    auto alloc = [&](size_t bytes) -> void* {
        void* p = ws + off;
        off += (bytes + 511) & ~(size_t)511;
        return p;
    };
    // persistent region
    int4* rec = (int4*)alloc((size_t)N_NODES * 16);
    float* dinv = (float*)alloc((size_t)N_NODES * 4);
    int* gcursor = (int*)alloc(NB * 4);
    int* csrc = (int*)alloc(((size_t)N_EDGES + 64) * 4);  // +64 overread slack
    // transient union: staging (16MB) dead after k_build; zA overlays it.
    // z buffers have N_NODES+1 rows; row N_NODES is the zero row.
    size_t zbytes = (size_t)(N_NODES + 1) * DIM * 2;  // 12.81 MB
    size_t stbytes = (size_t)NB * CAP * 4;            // 16.05 MB
    char* transient = (char*)alloc(stbytes > zbytes ? stbytes : zbytes);
    int* staging = (int*)transient;
    __half* zA = (__half*)transient;
    __half* zB = (__half*)alloc(zbytes);

    hipMemsetAsync(gcursor, 0, NB * 4, stream);

    k_bucket<<<NBLK1, 512, 0, stream>>>(ei, gcursor, staging);
    k_build<<<NB, 1024, 0, stream>>>(gcursor, staging, rec, dinv, csrc);
    // staging dead from here; zA overlays it. Tail threads zero zero-rows.
    k_z0<<<(N_NODES * DIM / 4) / 256 + 1, 256, 0, stream>>>(emb, dinv, zA, zB);

    int spmvBlocks = (N_NODES + 3) / 4;  // 4 waves/block, 1 wave/node
    // pass1: zA -> zB (z2); pass2: zB -> zA (z3); pass3: gathers zA, reads
    // zB(z2)+zA(z3) own rows, writes out.
    k_spmv<<<spmvBlocks, 256, 0, stream>>>(rec, csrc, zA, zB, nullptr, emb, out, 0);
    k_spmv<<<spmvBlocks, 256, 0, stream>>>(rec, csrc, zB, zA, nullptr, emb, out, 0);
    k_spmv<<<spmvBlocks, 256, 0, stream>>>(rec, csrc, zA, nullptr, zB, emb, out, 2);
}